// Round 7
// baseline (940.668 us; speedup 1.0000x reference)
//
#include <hip/hip_runtime.h>
#include <math.h>

#define BATCH 32
#define TLEN 8192
#define NCH 64           // chunks
#define CLEN 128         // steps per chunk
#define SUBL 8           // steps per sub-chunk
#define NSUB 16          // sub-chunks per chunk
#define NROWS (BATCH*TLEN)   // 262144 rows

typedef _Float16 h2 __attribute__((ext_vector_type(2)));
union HU { unsigned int u; h2 h; };
__device__ __forceinline__ h2 u2h(unsigned int x) { HU t; t.u = x; return t.h; }
__device__ __forceinline__ unsigned int pkh(float a, float b) {
    HU t; t.h = h2{(_Float16)a, (_Float16)b}; return t.u;
}

#if __has_builtin(__builtin_amdgcn_fdot2)
__device__ __forceinline__ float dot2f(h2 a, h2 b, float c) {
    return __builtin_amdgcn_fdot2(a, b, c, false);
}
#else
__device__ __forceinline__ float dot2f(h2 a, h2 b, float c) {
    return fmaf((float)a.x, (float)b.x, fmaf((float)a.y, (float)b.y, c));
}
#endif

__device__ __forceinline__ unsigned short f2bf(float f) {
    unsigned int u = __float_as_uint(f);
    u += 0x7FFFu + ((u >> 16) & 1u);       // round-to-nearest-even
    return (unsigned short)(u >> 16);
}
__device__ __forceinline__ float bf2f(unsigned short s) {
    return __uint_as_float(((unsigned int)s) << 16);
}

// ---------------------------------------------------------------------------
// HiPPO step: s <- (I - A/t) s + (x/t) * r
// ---------------------------------------------------------------------------
__device__ __forceinline__ void hippo_step(float s[8], float inv_t, float xb) {
    const float R[8] = {1.0f, 1.7320508075688772f, 2.23606797749979f,
                        2.6457513110645907f, 3.0f, 3.3166247903554f,
                        3.605551275463989f, 3.872983346207417f};
    float p = 0.0f;
    #pragma unroll
    for (int n = 0; n < 8; n++) {
        float sn = s[n];
        float as = fmaf(R[n], p, (float)(n + 1) * sn);
        s[n] = fmaf(-inv_t, as, fmaf(xb, R[n], sn));
        p = fmaf(R[n], sn, p);
    }
}

// ---------------------------------------------------------------------------
// Kernel A: per-chunk runs; dumps sub-chunk boundary data every SUBL steps.
// ---------------------------------------------------------------------------
__global__ void hippo_chunk_kernel(const float* __restrict__ x_seq,
                                   float* __restrict__ Psub,  // [NCH][NSUB][8][8]
                                   float* __restrict__ Vsub,  // [NCH][NSUB][64][8]
                                   float* __restrict__ Pfin,  // [NCH][8][8]
                                   float* __restrict__ Vfin)  // [NCH][64][8]
{
    int chunk = blockIdx.x;
    int tid = threadIdx.x;
    if (tid >= 72) return;
    bool isP = tid >= 64;
    int col = tid - 64;
    int b = tid >> 1, c = tid & 1;

    float s[8];
    #pragma unroll
    for (int n = 0; n < 8; n++) s[n] = (isP && n == col) ? 1.0f : 0.0f;

    int t0 = chunk * CLEN;
    for (int i = 0; i < CLEN; i++) {
        if ((i & (SUBL - 1)) == 0) {
            int sub = i >> 3;
            if (isP) {
                #pragma unroll
                for (int n = 0; n < 8; n++)
                    Psub[(((size_t)chunk * NSUB + sub) * 8 + n) * 8 + col] = s[n];
            } else {
                #pragma unroll
                for (int n = 0; n < 8; n++)
                    Vsub[(((size_t)chunk * NSUB + sub) * 64 + tid) * 8 + n] = s[n];
            }
        }
        float tf = (float)(t0 + i + 1);
        float inv_t = 1.0f / tf;
        float x = 0.0f;
        if (!isP) x = x_seq[((size_t)(b * TLEN + t0 + i)) * 2 + c];
        hippo_step(s, inv_t, x * inv_t);
    }
    if (isP) {
        #pragma unroll
        for (int n = 0; n < 8; n++) Pfin[((size_t)chunk * 8 + n) * 8 + col] = s[n];
    } else {
        #pragma unroll
        for (int n = 0; n < 8; n++) Vfin[((size_t)chunk * 64 + tid) * 8 + n] = s[n];
    }
}

// ---------------------------------------------------------------------------
// Kernel B: sequential composition across 64 chunks. One thread per (b,c).
// ---------------------------------------------------------------------------
__global__ void hippo_compose_kernel(const float* __restrict__ Pfin,
                                     const float* __restrict__ Vfin,
                                     float* __restrict__ S0)   // [NCH][64][8]
{
    int tid = threadIdx.x;   // 0..63
    float s[8];
    #pragma unroll
    for (int n = 0; n < 8; n++) s[n] = 0.0f;

    #pragma unroll 2
    for (int chunk = 0; chunk < NCH; chunk++) {
        #pragma unroll
        for (int n = 0; n < 8; n++) S0[((size_t)chunk * 64 + tid) * 8 + n] = s[n];
        float ns[8];
        #pragma unroll
        for (int n = 0; n < 8; n++) {
            float acc = Vfin[((size_t)chunk * 64 + tid) * 8 + n];
            #pragma unroll
            for (int m = 0; m < 8; m++)
                acc = fmaf(Pfin[((size_t)chunk * 8 + n) * 8 + m], s[m], acc);
            ns[n] = acc;
        }
        #pragma unroll
        for (int n = 0; n < 8; n++) s[n] = ns[n];
    }
}

// ---------------------------------------------------------------------------
// Kernel C: fine expand, plane-major bf16 output hT[16][NROWS].
// Each thread buffers its 8 steps, then stores one dwordx4 (8 bf16) per plane.
// ---------------------------------------------------------------------------
__global__ __launch_bounds__(256) void hippo_expand_kernel(
    const float* __restrict__ x_seq,
    const float* __restrict__ Psub,
    const float* __restrict__ Vsub,
    const float* __restrict__ S0,
    unsigned short* __restrict__ hT)     // [16][NROWS] bf16
{
    int tid = threadIdx.x;
    int sub = tid & 15;
    int c = (tid >> 4) & 1;
    int blo = tid >> 5;                  // 0..7
    int bhi = blockIdx.x & 3;            // 0..3
    int chunk = blockIdx.x >> 2;         // 0..63
    int b = bhi * 8 + blo;
    int seq = b * 2 + c;

    float s0v[8];
    #pragma unroll
    for (int n = 0; n < 8; n++)
        s0v[n] = S0[((size_t)chunk * 64 + seq) * 8 + n];

    const float* Pp = &Psub[((size_t)chunk * NSUB + sub) * 64];
    const float* Vp = &Vsub[(((size_t)chunk * NSUB + sub) * 64 + seq) * 8];

    float s[8];
    #pragma unroll
    for (int n = 0; n < 8; n++) {
        float acc = Vp[n];
        #pragma unroll
        for (int m = 0; m < 8; m++)
            acc = fmaf(Pp[n * 8 + m], s0v[m], acc);
        s[n] = acc;
    }

    int t0 = chunk * CLEN + sub * SUBL;
    size_t rowbase = (size_t)b * TLEN;

    unsigned int pk[8][4];               // [plane n][dword of 8 bf16]
    #pragma unroll
    for (int i = 0; i < SUBL; i++) {
        int t = t0 + i;
        float tf = (float)(t + 1);
        float inv_t = 1.0f / tf;
        float x = x_seq[(rowbase + t) * 2 + c];
        hippo_step(s, inv_t, x * inv_t);
        #pragma unroll
        for (int n = 0; n < 8; n++) {
            unsigned int us = (unsigned int)f2bf(s[n]);
            if ((i & 1) == 0) pk[n][i >> 1] = us;
            else              pk[n][i >> 1] |= us << 16;
        }
    }
    #pragma unroll
    for (int n = 0; n < 8; n++) {
        uint4* dst = (uint4*)&hT[(size_t)(c * 8 + n) * NROWS + rowbase + t0];
        *dst = make_uint4(pk[n][0], pk[n][1], pk[n][2], pk[n][3]);
    }
}

// ---------------------------------------------------------------------------
// KAN helpers
// ---------------------------------------------------------------------------
__device__ __forceinline__ void bspline4(float x, float& B0, float& B1,
                                         float& B2, float& B3, int& m)
{
    float tt = fmaf(x, 5.0f, 8.0f);        // (x + 1.6) * 5
    float fm = floorf(tt);
    float u = tt - fm;
    bool valid = (fm >= 0.0f) && (fm <= 15.0f);
    float u2 = u * u, u3 = u2 * u;
    float um = 1.0f - u;
    B0 = um * um * um * (1.0f / 6.0f);
    B3 = u3 * (1.0f / 6.0f);
    B1 = fmaf(3.0f, u3, fmaf(-6.0f, u2, 4.0f)) * (1.0f / 6.0f);
    B2 = fmaf(-3.0f, u3, fmaf(3.0f, u2, fmaf(3.0f, u, 1.0f))) * (1.0f / 6.0f);
    float msk = valid ? 1.0f : 0.0f;
    B0 *= msk; B1 *= msk; B2 *= msk; B3 *= msk;
    m = valid ? (int)fm : 0;
}

__device__ __forceinline__ float silu(float x) {
    return x / (1.0f + __expf(-x));
}

// All-register activations: layer1 rolled-i (LDS-fed), layer2 i-UNROLLED so
// acc1[i] stays a static register index (no out1T round-trip at all).
// sched_barrier(0) between layer-2 iterations bounds scheduler hoisting
// (round-3 lesson: unbounded straight-line hoisting -> 256-VGPR spill).
// LDS 39936 B (wb as f16 pairs) -> 4 blocks/CU candidate.
__global__ __launch_bounds__(256, 2) void kan_kernel(
    const unsigned short* __restrict__ hT,   // [16][NROWS] bf16
    const float* __restrict__ wb1, const float* __restrict__ ws1,
    const float* __restrict__ wb2, const float* __restrict__ ws2,
    const float* __restrict__ wb3, const float* __restrict__ ws3,
    float* __restrict__ out)
{
    // phase1: W1 f16-pairs [i<16][o<32][19] @0..9728, wbT1 f16-pairs @9728..9984
    // phase2: W2 f16-pairs [i<32][o<16][19] @0..9728, wbT2 f16-pairs @9728..9984
    __shared__ unsigned int wldsU[9984];     // 39936 B
    int tid = threadIdx.x;
    int row = blockIdx.x * 256 + tid;

    // ---- stage phase 1
    for (int idx = tid; idx < 9984; idx += 256) {
        unsigned int v;
        if (idx < 9728) {
            int i = idx / 608;
            int r = idx - i * 608;
            int o = r / 19;
            int p = r - o * 19;
            int j0 = (p < 10) ? (2 * p) : (2 * (p - 10) + 1);
            int j1 = j0 + 1;
            float lo = (j0 >= 3 && j0 <= 15) ? ws1[o * 208 + i * 13 + (j0 - 3)] : 0.0f;
            float hi = (j1 >= 3 && j1 <= 15) ? ws1[o * 208 + i * 13 + (j1 - 3)] : 0.0f;
            v = pkh(lo, hi);
        } else {
            int k = idx - 9728;          // 0..255
            int i = k >> 4, p = k & 15;  // i<16, pair p -> (o=2p, 2p+1)
            v = pkh(wb1[(2 * p) * 16 + i], wb1[(2 * p + 1) * 16 + i]);
        }
        wldsU[idx] = v;
    }
    __syncthreads();

    // ---- layer 1: 16 -> 32 (rolled i, 2-deep bf16 input prefetch)
    float acc1[32];
    #pragma unroll
    for (int o = 0; o < 32; o++) acc1[o] = 0.0f;

    unsigned short xc = hT[row];
    unsigned short xn = hT[(size_t)NROWS + row];
    #pragma unroll 1
    for (int i = 0; i < 16; i++) {
        unsigned short xf = hT[(size_t)((i + 2) & 15) * NROWS + row];
        float xv = bf2f(xc);
        float sx = silu(xv);
        float B0, B1, B2, B3; int m;
        bspline4(xv, B0, B1, B2, B3, m);
        h2 B01 = u2h(pkh(B0, B1));
        h2 B23 = u2h(pkh(B2, B3));
        int poff = (m & 1) ? (10 + ((m - 1) >> 1)) : (m >> 1);
        int base = i * 608 + poff;
        #pragma unroll
        for (int o = 0; o < 32; o++) {
            unsigned int da = wldsU[base + o * 19];
            unsigned int db = wldsU[base + o * 19 + 1];
            float a = acc1[o];
            a = dot2f(B01, u2h(da), a);
            a = dot2f(B23, u2h(db), a);
            acc1[o] = a;
        }
        int wbb = 9728 + i * 16;
        #pragma unroll
        for (int p = 0; p < 16; p++) {
            h2 wpair = u2h(wldsU[wbb + p]);
            acc1[2 * p]     = fmaf(sx, (float)wpair.x, acc1[2 * p]);
            acc1[2 * p + 1] = fmaf(sx, (float)wpair.y, acc1[2 * p + 1]);
        }
        xc = xn; xn = xf;
    }
    __syncthreads();   // all waves done reading phase-1 weights

    // ---- stage phase 2
    for (int idx = tid; idx < 9984; idx += 256) {
        unsigned int v;
        if (idx < 9728) {
            int i = idx / 304;
            int r = idx - i * 304;
            int o = r / 19;
            int p = r - o * 19;
            int j0 = (p < 10) ? (2 * p) : (2 * (p - 10) + 1);
            int j1 = j0 + 1;
            float lo = (j0 >= 3 && j0 <= 15) ? ws2[o * 416 + i * 13 + (j0 - 3)] : 0.0f;
            float hi = (j1 >= 3 && j1 <= 15) ? ws2[o * 416 + i * 13 + (j1 - 3)] : 0.0f;
            v = pkh(lo, hi);
        } else {
            int k = idx - 9728;          // 0..255
            int i = k >> 3, p = k & 7;   // i<32, pair p -> (o=2p, 2p+1)
            v = pkh(wb2[(2 * p) * 32 + i], wb2[(2 * p + 1) * 32 + i]);
        }
        wldsU[idx] = v;
    }
    __syncthreads();

    // ---- layer 2: 32 -> 16, i fully unrolled (acc1 static), o rolled-unrolled
    float acc2[16];
    #pragma unroll
    for (int o = 0; o < 16; o++) acc2[o] = 0.0f;

    #pragma unroll
    for (int i = 0; i < 32; i++) {
        float yv = acc1[i];
        float sx = silu(yv);
        float B0, B1, B2, B3; int m;
        bspline4(yv, B0, B1, B2, B3, m);
        h2 B01 = u2h(pkh(B0, B1));
        h2 B23 = u2h(pkh(B2, B3));
        int poff = (m & 1) ? (10 + ((m - 1) >> 1)) : (m >> 1);
        int base = i * 304 + poff;
        #pragma unroll
        for (int o = 0; o < 16; o++) {
            unsigned int da = wldsU[base + o * 19];
            unsigned int db = wldsU[base + o * 19 + 1];
            float a = acc2[o];
            a = dot2f(B01, u2h(da), a);
            a = dot2f(B23, u2h(db), a);
            acc2[o] = a;
        }
        int wbb = 9728 + i * 8;
        #pragma unroll
        for (int p = 0; p < 8; p++) {
            h2 wpair = u2h(wldsU[wbb + p]);
            acc2[2 * p]     = fmaf(sx, (float)wpair.x, acc2[2 * p]);
            acc2[2 * p + 1] = fmaf(sx, (float)wpair.y, acc2[2 * p + 1]);
        }
        __builtin_amdgcn_sched_barrier(0);   // bound cross-iteration hoisting
    }

    // ---- layer 3: 16 -> 1, fully unrolled, fp32 weights from global
    float acc3 = 0.0f;
    #pragma unroll
    for (int i = 0; i < 16; i++) {
        float xv = acc2[i];
        float sx = silu(xv);
        float B0, B1, B2, B3; int m;
        bspline4(xv, B0, B1, B2, B3, m);
        acc3 = fmaf(sx, wb3[i], acc3);
        const float* w3 = &ws3[i * 13];
        int j0 = m - 3;
        float w0v = (j0 >= 0)              ? w3[j0]     : 0.0f;
        float w1v = (j0 >= -1 && j0 <= 11) ? w3[j0 + 1] : 0.0f;
        float w2v = (j0 >= -2 && j0 <= 10) ? w3[j0 + 2] : 0.0f;
        float w3v = (j0 <= 9)              ? w3[j0 + 3] : 0.0f;
        acc3 = fmaf(B0, w0v, acc3);
        acc3 = fmaf(B1, w1v, acc3);
        acc3 = fmaf(B2, w2v, acc3);
        acc3 = fmaf(B3, w3v, acc3);
    }
    out[row] = acc3;
}

// ---------------------------------------------------------------------------
extern "C" void kernel_launch(void* const* d_in, const int* in_sizes, int n_in,
                              void* d_out, int out_size, void* d_ws, size_t ws_size,
                              hipStream_t stream) {
    const float* x_seq = (const float*)d_in[0];
    const float* wb1   = (const float*)d_in[1];
    const float* ws1   = (const float*)d_in[2];
    const float* wb2   = (const float*)d_in[3];
    const float* ws2   = (const float*)d_in[4];
    const float* wb3   = (const float*)d_in[5];
    const float* ws3   = (const float*)d_in[6];

    float* ws   = (float*)d_ws;
    float* Psub = ws;                   // 64*16*64        =   65536
    float* Vsub = ws + 65536;           // 64*16*64*8      =  524288
    float* Pfin = ws + 589824;          // 64*64           =    4096
    float* Vfin = ws + 593920;          // 64*64*8         =   32768
    float* S0   = ws + 626688;          // 64*64*8         =   32768
    unsigned short* hT = (unsigned short*)(ws + 659456);   // 16*262144 bf16 = 8 MB
    float* out  = (float*)d_out;

    hipLaunchKernelGGL(hippo_chunk_kernel,   dim3(NCH), dim3(128), 0, stream,
                       x_seq, Psub, Vsub, Pfin, Vfin);
    hipLaunchKernelGGL(hippo_compose_kernel, dim3(1),   dim3(64),  0, stream,
                       Pfin, Vfin, S0);
    hipLaunchKernelGGL(hippo_expand_kernel,  dim3(NCH * 4), dim3(256), 0, stream,
                       x_seq, Psub, Vsub, S0, hT);
    hipLaunchKernelGGL(kan_kernel, dim3(NROWS / 256), dim3(256), 0, stream,
                       hT, wb1, ws1, wb2, ws2, wb3, ws3, out);
}

// Round 8
// 135.969 us; speedup vs baseline: 6.9183x; 6.9183x over previous
//
#include <hip/hip_runtime.h>
#include <math.h>

#define BATCH 32
#define TLEN 8192
#define NCH 64           // chunks
#define CLEN 128         // steps per chunk
#define SUBL 8           // steps per sub-chunk
#define NSUB 16          // sub-chunks per chunk
#define NROWS (BATCH*TLEN)   // 262144 rows

typedef _Float16 h2 __attribute__((ext_vector_type(2)));
union HU { unsigned int u; h2 h; };
__device__ __forceinline__ h2 u2h(unsigned int x) { HU t; t.u = x; return t.h; }
__device__ __forceinline__ unsigned int pkh(float a, float b) {
    HU t; t.h = h2{(_Float16)a, (_Float16)b}; return t.u;
}

#if __has_builtin(__builtin_amdgcn_fdot2)
__device__ __forceinline__ float dot2f(h2 a, h2 b, float c) {
    return __builtin_amdgcn_fdot2(a, b, c, false);
}
#else
__device__ __forceinline__ float dot2f(h2 a, h2 b, float c) {
    return fmaf((float)a.x, (float)b.x, fmaf((float)a.y, (float)b.y, c));
}
#endif

// ---------------------------------------------------------------------------
// HiPPO step, tree-form prefix: s <- (I - A/t) s + (x/t) * r
// (A s)[n] = (n+1)*s[n] + r[n] * p[n],  p[n] = sum_{m<n} r[m] s[m]
// ---------------------------------------------------------------------------
__device__ __forceinline__ void hippo_step(float s[8], float inv_t, float xb) {
    const float R[8] = {1.0f, 1.7320508075688772f, 2.23606797749979f,
                        2.6457513110645907f, 3.0f, 3.3166247903554f,
                        3.605551275463989f, 3.872983346207417f};
    float q0 = R[0]*s[0], q1 = R[1]*s[1], q2 = R[2]*s[2], q3 = R[3]*s[3];
    float q4 = R[4]*s[4], q5 = R[5]*s[5], q6 = R[6]*s[6];
    float t01 = q0+q1, t23 = q2+q3, t45 = q4+q5;
    float p1 = q0, p2 = t01, p3 = t01+q2, p4 = t01+t23;
    float p5 = p4+q4, p6 = p4+t45, p7 = p6+q6;
    float p[8] = {0.0f, p1, p2, p3, p4, p5, p6, p7};
    #pragma unroll
    for (int n = 0; n < 8; n++) {
        float as = fmaf(R[n], p[n], (float)(n + 1) * s[n]);
        s[n] = fmaf(-inv_t, as, fmaf(xb, R[n], s[n]));
    }
}

// ---------------------------------------------------------------------------
// Kernel A: per-chunk runs; dumps sub-chunk boundary data every SUBL steps.
// ---------------------------------------------------------------------------
__global__ void hippo_chunk_kernel(const float* __restrict__ x_seq,
                                   float* __restrict__ Psub,  // [NCH][NSUB][8][8]
                                   float* __restrict__ Vsub,  // [NCH][NSUB][64][8]
                                   float* __restrict__ Pfin,  // [NCH][8][8]
                                   float* __restrict__ Vfin)  // [NCH][64][8]
{
    int chunk = blockIdx.x;
    int tid = threadIdx.x;
    if (tid >= 72) return;
    bool isP = tid >= 64;
    int col = tid - 64;
    int b = tid >> 1, c = tid & 1;

    float s[8];
    #pragma unroll
    for (int n = 0; n < 8; n++) s[n] = (isP && n == col) ? 1.0f : 0.0f;

    int t0 = chunk * CLEN;
    for (int i = 0; i < CLEN; i++) {
        if ((i & (SUBL - 1)) == 0) {
            int sub = i >> 3;
            if (isP) {
                #pragma unroll
                for (int n = 0; n < 8; n++)
                    Psub[(((size_t)chunk * NSUB + sub) * 8 + n) * 8 + col] = s[n];
            } else {
                #pragma unroll
                for (int n = 0; n < 8; n++)
                    Vsub[(((size_t)chunk * NSUB + sub) * 64 + tid) * 8 + n] = s[n];
            }
        }
        float tf = (float)(t0 + i + 1);
        float inv_t = 1.0f / tf;
        float x = 0.0f;
        if (!isP) x = x_seq[((size_t)(b * TLEN + t0 + i)) * 2 + c];
        hippo_step(s, inv_t, x * inv_t);
    }
    if (isP) {
        #pragma unroll
        for (int n = 0; n < 8; n++) Pfin[((size_t)chunk * 8 + n) * 8 + col] = s[n];
    } else {
        #pragma unroll
        for (int n = 0; n < 8; n++) Vfin[((size_t)chunk * 64 + tid) * 8 + n] = s[n];
    }
}

// ---------------------------------------------------------------------------
// Kernel B (fused compose+expand): each block composes its chunk's start
// state (redundant small prefix walk, threads 0..15), then fine-expands,
// writing f16-pair planes hTu[8][NROWS] (plane p = features 2p,2p+1).
// ---------------------------------------------------------------------------
__global__ __launch_bounds__(256) void hippo_expand_kernel(
    const float* __restrict__ x_seq,
    const float* __restrict__ Psub,
    const float* __restrict__ Vsub,
    const float* __restrict__ Pfin,
    const float* __restrict__ Vfin,
    unsigned int* __restrict__ hTu)      // [8][NROWS] f16-pairs
{
    __shared__ float sLDS[16][8];
    int tid = threadIdx.x;
    int sub = tid & 15;
    int c = (tid >> 4) & 1;
    int blo = tid >> 5;                  // 0..7
    int bhi = blockIdx.x & 3;            // 0..3
    int chunk = blockIdx.x >> 2;         // 0..63
    int b = bhi * 8 + blo;
    int seq = b * 2 + c;

    // ---- compose prefix for this block's 16 seqs
    if (tid < 16) {
        int useq = (bhi * 8 + (tid >> 1)) * 2 + (tid & 1);
        float s[8];
        #pragma unroll
        for (int n = 0; n < 8; n++) s[n] = 0.0f;
        for (int ck = 0; ck < 64; ck++) {
            if (ck >= chunk) break;
            float ns[8];
            #pragma unroll
            for (int n = 0; n < 8; n++) {
                float acc = Vfin[((size_t)ck * 64 + useq) * 8 + n];
                #pragma unroll
                for (int m = 0; m < 8; m++)
                    acc = fmaf(Pfin[((size_t)ck * 8 + n) * 8 + m], s[m], acc);
                ns[n] = acc;
            }
            #pragma unroll
            for (int n = 0; n < 8; n++) s[n] = ns[n];
        }
        #pragma unroll
        for (int n = 0; n < 8; n++) sLDS[tid][n] = s[n];
    }
    __syncthreads();

    float s0v[8];
    {
        int u = blo * 2 + c;
        #pragma unroll
        for (int n = 0; n < 8; n++) s0v[n] = sLDS[u][n];
    }

    const float* Pp = &Psub[((size_t)chunk * NSUB + sub) * 64];
    const float* Vp = &Vsub[(((size_t)chunk * NSUB + sub) * 64 + seq) * 8];

    float s[8];
    #pragma unroll
    for (int n = 0; n < 8; n++) {
        float acc = Vp[n];
        #pragma unroll
        for (int m = 0; m < 8; m++)
            acc = fmaf(Pp[n * 8 + m], s0v[m], acc);
        s[n] = acc;
    }

    int t0 = chunk * CLEN + sub * SUBL;
    size_t rowbase = (size_t)b * TLEN;

    unsigned int dw[4][8];               // [pair k][step t]
    #pragma unroll
    for (int i = 0; i < SUBL; i++) {
        int t = t0 + i;
        float tf = (float)(t + 1);
        float inv_t = 1.0f / tf;
        float x = x_seq[(rowbase + t) * 2 + c];
        hippo_step(s, inv_t, x * inv_t);
        #pragma unroll
        for (int k = 0; k < 4; k++)
            dw[k][i] = pkh(s[2 * k], s[2 * k + 1]);
    }
    #pragma unroll
    for (int k = 0; k < 4; k++) {
        int plane = c * 4 + k;
        uint4* dst = (uint4*)&hTu[(size_t)plane * NROWS + rowbase + t0];
        dst[0] = make_uint4(dw[k][0], dw[k][1], dw[k][2], dw[k][3]);
        dst[1] = make_uint4(dw[k][4], dw[k][5], dw[k][6], dw[k][7]);
    }
}

// ---------------------------------------------------------------------------
// KAN helpers
// ---------------------------------------------------------------------------
__device__ __forceinline__ void bspline4(float x, float& B0, float& B1,
                                         float& B2, float& B3, int& m)
{
    float tt = fmaf(x, 5.0f, 8.0f);        // (x + 1.6) * 5
    float fm = floorf(tt);
    float u = tt - fm;
    bool valid = (fm >= 0.0f) && (fm <= 15.0f);
    float u2 = u * u, u3 = u2 * u;
    float um = 1.0f - u;
    B0 = um * um * um * (1.0f / 6.0f);
    B3 = u3 * (1.0f / 6.0f);
    B1 = fmaf(3.0f, u3, fmaf(-6.0f, u2, 4.0f)) * (1.0f / 6.0f);
    B2 = fmaf(-3.0f, u3, fmaf(3.0f, u2, fmaf(3.0f, u, 1.0f))) * (1.0f / 6.0f);
    float msk = valid ? 1.0f : 0.0f;
    B0 *= msk; B1 *= msk; B2 *= msk; B3 *= msk;
    m = valid ? (int)fm : 0;
}

__device__ __forceinline__ float silu(float x) {
    return x / (1.0f + __expf(-x));
}

// Round-6 skeleton: rolled pair-loops, f16-pair activations, LDS = spline
// weights only (38912 B -> 4 blocks/CU). wb from global (uniform scalar
// loads). Staging is fully affine: no integer div/mod anywhere.
__global__ __launch_bounds__(256) void kan_kernel(
    const unsigned int* __restrict__ hTu,    // [8][NROWS] f16 pairs
    unsigned int* __restrict__ out1Tu,       // [16][NROWS] f16 pairs
    const float* __restrict__ wb1, const float* __restrict__ ws1,
    const float* __restrict__ wb2, const float* __restrict__ ws2,
    const float* __restrict__ wb3, const float* __restrict__ ws3,
    float* __restrict__ out)
{
    // phase1: W1 f16-pairs [i<16][o<32][p<19]; phase2: W2 [i<32][o<16][p<19]
    __shared__ unsigned int wldsU[9728];     // 38912 B
    int tid = threadIdx.x;
    int row = blockIdx.x * 256 + tid;

    // ---- stage phase 1 (affine: i = tid>>4, two o's per thread)
    {
        int i = tid >> 4, q = tid & 15;
        #pragma unroll
        for (int oo = 0; oo < 2; oo++) {
            int o = q + oo * 16;
            const float* src = ws1 + o * 208 + i * 13;
            int dst = i * 608 + o * 19;
            #pragma unroll
            for (int p = 0; p < 19; p++) {
                int j0 = (p < 10) ? (2 * p) : (2 * (p - 10) + 1);
                float lo = (j0 >= 3 && j0 <= 15) ? src[j0 - 3] : 0.0f;
                float hi = (j0 + 1 >= 3 && j0 + 1 <= 15) ? src[j0 - 2] : 0.0f;
                wldsU[dst + p] = pkh(lo, hi);
            }
        }
    }
    __syncthreads();

    // ---- layer 1: 16 -> 32 (rolled over 8 input pairs)
    float acc1[32];
    #pragma unroll
    for (int o = 0; o < 32; o++) acc1[o] = 0.0f;

    unsigned int cur = hTu[row];
    unsigned int nxt = hTu[(size_t)NROWS + row];
    #pragma unroll 1
    for (int pi = 0; pi < 8; pi++) {
        unsigned int fut = hTu[(size_t)((pi + 2) & 7) * NROWS + row];
        h2 xp = u2h(cur);
        #pragma unroll
        for (int par = 0; par < 2; par++) {
            int i = 2 * pi + par;
            float xv = (par == 0) ? (float)xp.x : (float)xp.y;
            float sx = silu(xv);
            float B0, B1, B2, B3; int m;
            bspline4(xv, B0, B1, B2, B3, m);
            h2 B01 = u2h(pkh(B0, B1));
            h2 B23 = u2h(pkh(B2, B3));
            int poff = (m & 1) ? (10 + ((m - 1) >> 1)) : (m >> 1);
            int base = i * 608 + poff;
            const float* wbrow = wb1 + i;       // wb1[o*16+i]
            #pragma unroll
            for (int o = 0; o < 32; o++) {
                unsigned int da = wldsU[base + o * 19];
                unsigned int db = wldsU[base + o * 19 + 1];
                float a = acc1[o];
                a = dot2f(B01, u2h(da), a);
                a = dot2f(B23, u2h(db), a);
                a = fmaf(sx, wbrow[o * 16], a);
                acc1[o] = a;
            }
        }
        cur = nxt; nxt = fut;
    }
    #pragma unroll
    for (int op = 0; op < 16; op++)
        out1Tu[(size_t)op * NROWS + row] = pkh(acc1[2 * op], acc1[2 * op + 1]);

    __syncthreads();   // all waves done reading phase-1 weights

    // ---- stage phase 2 (affine: i = tid>>3, two o's per thread)
    {
        int i = tid >> 3, q = tid & 7;
        #pragma unroll
        for (int oo = 0; oo < 2; oo++) {
            int o = q + oo * 8;
            const float* src = ws2 + o * 416 + i * 13;
            int dst = i * 304 + o * 19;
            #pragma unroll
            for (int p = 0; p < 19; p++) {
                int j0 = (p < 10) ? (2 * p) : (2 * (p - 10) + 1);
                float lo = (j0 >= 3 && j0 <= 15) ? src[j0 - 3] : 0.0f;
                float hi = (j0 + 1 >= 3 && j0 + 1 <= 15) ? src[j0 - 2] : 0.0f;
                wldsU[dst + p] = pkh(lo, hi);
            }
        }
    }
    __syncthreads();

    // ---- layer 2: 32 -> 16 (rolled over 16 input pairs)
    float acc2[16];
    #pragma unroll
    for (int o = 0; o < 16; o++) acc2[o] = 0.0f;

    cur = out1Tu[row];
    nxt = out1Tu[(size_t)NROWS + row];
    #pragma unroll 1
    for (int pi = 0; pi < 16; pi++) {
        unsigned int fut = out1Tu[(size_t)((pi + 2) & 15) * NROWS + row];
        h2 yp = u2h(cur);
        #pragma unroll
        for (int par = 0; par < 2; par++) {
            int i = 2 * pi + par;
            float yv = (par == 0) ? (float)yp.x : (float)yp.y;
            float sx = silu(yv);
            float B0, B1, B2, B3; int m;
            bspline4(yv, B0, B1, B2, B3, m);
            h2 B01 = u2h(pkh(B0, B1));
            h2 B23 = u2h(pkh(B2, B3));
            int poff = (m & 1) ? (10 + ((m - 1) >> 1)) : (m >> 1);
            int base = i * 304 + poff;
            const float* wbrow = wb2 + i;       // wb2[o*32+i]
            #pragma unroll
            for (int o = 0; o < 16; o++) {
                unsigned int da = wldsU[base + o * 19];
                unsigned int db = wldsU[base + o * 19 + 1];
                float a = acc2[o];
                a = dot2f(B01, u2h(da), a);
                a = dot2f(B23, u2h(db), a);
                a = fmaf(sx, wbrow[o * 32], a);
                acc2[o] = a;
            }
        }
        cur = nxt; nxt = fut;
    }

    // ---- layer 3: 16 -> 1, fully unrolled, fp32 weights from global
    float acc3 = 0.0f;
    #pragma unroll
    for (int i = 0; i < 16; i++) {
        float xv = acc2[i];
        float sx = silu(xv);
        float B0, B1, B2, B3; int m;
        bspline4(xv, B0, B1, B2, B3, m);
        acc3 = fmaf(sx, wb3[i], acc3);
        const float* w3 = &ws3[i * 13];
        int j0 = m - 3;
        float w0v = (j0 >= 0)              ? w3[j0]     : 0.0f;
        float w1v = (j0 >= -1 && j0 <= 11) ? w3[j0 + 1] : 0.0f;
        float w2v = (j0 >= -2 && j0 <= 10) ? w3[j0 + 2] : 0.0f;
        float w3v = (j0 <= 9)              ? w3[j0 + 3] : 0.0f;
        acc3 = fmaf(B0, w0v, acc3);
        acc3 = fmaf(B1, w1v, acc3);
        acc3 = fmaf(B2, w2v, acc3);
        acc3 = fmaf(B3, w3v, acc3);
    }
    out[row] = acc3;
}

// ---------------------------------------------------------------------------
extern "C" void kernel_launch(void* const* d_in, const int* in_sizes, int n_in,
                              void* d_out, int out_size, void* d_ws, size_t ws_size,
                              hipStream_t stream) {
    const float* x_seq = (const float*)d_in[0];
    const float* wb1   = (const float*)d_in[1];
    const float* ws1   = (const float*)d_in[2];
    const float* wb2   = (const float*)d_in[3];
    const float* ws2   = (const float*)d_in[4];
    const float* wb3   = (const float*)d_in[5];
    const float* ws3   = (const float*)d_in[6];

    float* ws   = (float*)d_ws;
    float* Psub = ws;                   // 64*16*64        =   65536
    float* Vsub = ws + 65536;           // 64*16*64*8      =  524288
    float* Pfin = ws + 589824;          // 64*64           =    4096
    float* Vfin = ws + 593920;          // 64*64*8         =   32768
    unsigned int* hTu    = (unsigned int*)(ws + 626688);   // 8*262144  = 2097152 dw
    unsigned int* out1Tu = (unsigned int*)(ws + 2723840);  // 16*262144 = 4194304 dw
    float* out  = (float*)d_out;

    hipLaunchKernelGGL(hippo_chunk_kernel,   dim3(NCH), dim3(128), 0, stream,
                       x_seq, Psub, Vsub, Pfin, Vfin);
    hipLaunchKernelGGL(hippo_expand_kernel,  dim3(NCH * 4), dim3(256), 0, stream,
                       x_seq, Psub, Vsub, Pfin, Vfin, hTu);
    hipLaunchKernelGGL(kan_kernel, dim3(NROWS / 256), dim3(256), 0, stream,
                       hTu, out1Tu, wb1, ws1, wb2, ws2, wb3, ws3, out);
}